// Round 15
// baseline (743.157 us; speedup 1.0000x reference)
//
#include <hip/hip_runtime.h>
#include <hip/hip_bf16.h>

// COO SpMM scatter-add: y[row[i]] += value[i] * x[col[i]], D=64.
// Round 5-14: packed v2f32 atomics — 32 lanes per nonzero, each lane owns 2
// features and issues ONE global_atomic_pk_add_f32 (8B RMW) instead of two
// 4B atomics. Halves the atomic op count (102.4M -> 51.2M); round-4 counters
// showed we sit at ~96% of the fabric atomic-op-rate ceiling.

#define D 64

typedef float floatx2 __attribute__((ext_vector_type(2)));

__device__ __forceinline__ void atomic_add_f32x2(float* addr, float a, float b) {
#if __has_builtin(__builtin_amdgcn_global_atomic_fadd_v2f32)
  floatx2 v = {a, b};
  __builtin_amdgcn_global_atomic_fadd_v2f32(
      (__attribute__((address_space(1))) floatx2*)addr, v);
#else
  atomicAdd(addr + 0, a);
  atomicAdd(addr + 1, b);
#endif
}

__global__ __launch_bounds__(256) void spmm_scatter_pk_kernel(
    const float* __restrict__ x,
    const int* __restrict__ row,
    const int* __restrict__ col,
    const float* __restrict__ value,
    float* __restrict__ y,
    int nnz) {
  long long gid = (long long)blockIdx.x * blockDim.x + threadIdx.x;
  int  half = (int)(gid & 31);        // 32 lanes per nnz, 2 features each
  long long i = gid >> 5;             // nonzero index
  if (i >= nnz) return;

  int   r = row[i];
  int   c = col[i];
  float v = value[i];

  const float2 xv = *(const float2*)&x[(size_t)c * D + half * 2];
  atomic_add_f32x2(&y[(size_t)r * D + half * 2], v * xv.x, v * xv.y);
}

extern "C" void kernel_launch(void* const* d_in, const int* in_sizes, int n_in,
                              void* d_out, int out_size, void* d_ws, size_t ws_size,
                              hipStream_t stream) {
  const float* x     = (const float*)d_in[0];
  const int*   row   = (const int*)d_in[1];
  const int*   col   = (const int*)d_in[2];
  const float* value = (const float*)d_in[3];

  float* y   = (float*)d_out;
  int    nnz = in_sizes[1];

  // d_out is poisoned with 0xAA before every timed launch — zero it.
  hipMemsetAsync(y, 0, (size_t)out_size * sizeof(float), stream);

  long long total_threads = (long long)nnz * 32;
  int block = 256;
  long long grid = (total_threads + block - 1) / block;
  spmm_scatter_pk_kernel<<<(int)grid, block, 0, stream>>>(x, row, col, value, y, nnz);
}

// Round 22
// 650.545 us; speedup vs baseline: 1.1424x; 1.1424x over previous
//
#include <hip/hip_runtime.h>

// COO SpMM: y[row[i]] += value[i] * x[col[i]], D=64, NNZ=1.6M, N=100k.
// Round 16-22: counting-sort-by-row + segmented reduce. Round-15 showed the
// atomic path is pinned at ~300 G atomic-ops/s (and pk-atomics are 4x worse
// per op), so we eliminate fp atomics entirely:
//   memset hist -> histogram -> single-block scan -> scatter (col,val) pairs
//   into row-sorted order -> per-row wave reduce with ONE plain store per row.
// Fallback to the verified 4B-atomic kernel if ws is too small.

#define D 64

// ---- fallback: round-4 kernel (348us verified) ----
__global__ __launch_bounds__(256) void spmm_scatter_kernel(
    const float* __restrict__ x, const int* __restrict__ row,
    const int* __restrict__ col, const float* __restrict__ value,
    float* __restrict__ y, int nnz) {
  long long gid = (long long)blockIdx.x * blockDim.x + threadIdx.x;
  int lane = (int)(gid & (D - 1));
  long long i = gid >> 6;
  if (i >= nnz) return;
  int r = row[i]; int c = col[i]; float v = value[i];
  atomicAdd(&y[(size_t)r * D + lane], v * x[(size_t)c * D + lane]);
}

// ---- sort pipeline ----
__global__ __launch_bounds__(256) void hist_kernel(
    const int* __restrict__ row, unsigned* __restrict__ hist, int nnz) {
  int i = blockIdx.x * blockDim.x + threadIdx.x;
  if (i < nnz) atomicAdd(&hist[row[i]], 1u);
}

// Single-block exclusive scan of hist[n] -> row_start[n] (+ a[n]=nnz), plus a
// second copy in cursor[] for the scatter phase. 1024 threads, chunked serial
// + Hillis-Steele block scan.
__global__ __launch_bounds__(1024) void scan_kernel(
    unsigned* __restrict__ a, unsigned* __restrict__ cursor, int n, int nnz) {
  const int tid = threadIdx.x;
  const int chunk = (n + 1023) >> 10;
  int lo = tid * chunk;
  int hi = lo + chunk; if (hi > n) hi = n;
  if (lo > n) lo = n;
  unsigned s = 0;
  for (int k = lo; k < hi; ++k) s += a[k];
  __shared__ unsigned part[1024];
  part[tid] = s;
  __syncthreads();
  for (int off = 1; off < 1024; off <<= 1) {
    unsigned t = (tid >= off) ? part[tid - off] : 0u;
    __syncthreads();
    part[tid] += t;
    __syncthreads();
  }
  unsigned run = (tid == 0) ? 0u : part[tid - 1];
  for (int k = lo; k < hi; ++k) {
    unsigned h = a[k];
    a[k] = run;
    cursor[k] = run;
    run += h;
  }
  if (tid == 0) a[n] = (unsigned)nnz;
}

__global__ __launch_bounds__(256) void scatter_kernel(
    const int* __restrict__ row, const int* __restrict__ col,
    const float* __restrict__ value, unsigned* __restrict__ cursor,
    int2* __restrict__ pairs, int nnz) {
  int i = blockIdx.x * blockDim.x + threadIdx.x;
  if (i >= nnz) return;
  int r = row[i];
  unsigned dst = atomicAdd(&cursor[r], 1u);
  pairs[dst] = make_int2(col[i], __float_as_int(value[i]));
}

// One wave per row; lane = feature. Register accumulate, single plain store.
__global__ __launch_bounds__(256) void reduce_kernel(
    const float* __restrict__ x, const unsigned* __restrict__ row_start,
    const int2* __restrict__ pairs, float* __restrict__ y, int n) {
  long long gid = (long long)blockIdx.x * blockDim.x + threadIdx.x;
  int lane = (int)(gid & (D - 1));
  long long r = gid >> 6;
  if (r >= n) return;
  unsigned s = row_start[r], e = row_start[r + 1];
  float acc = 0.f;
  for (unsigned j = s; j < e; ++j) {
    int2 p = pairs[j];                               // wave-uniform 8B broadcast
    acc += __int_as_float(p.y) * x[(size_t)p.x * D + lane];  // coalesced 256B
  }
  y[(size_t)r * D + lane] = acc;                     // plain store, no atomic
}

extern "C" void kernel_launch(void* const* d_in, const int* in_sizes, int n_in,
                              void* d_out, int out_size, void* d_ws, size_t ws_size,
                              hipStream_t stream) {
  const float* x     = (const float*)d_in[0];
  const int*   row   = (const int*)d_in[1];
  const int*   col   = (const int*)d_in[2];
  const float* value = (const float*)d_in[3];
  float* y   = (float*)d_out;
  int    nnz = in_sizes[1];
  int    n   = out_size / D;

  size_t need = (size_t)nnz * 8 + (size_t)(n + 1) * 4 + (size_t)n * 4;
  if (ws_size < need) {
    // Fallback: verified atomic path.
    hipMemsetAsync(y, 0, (size_t)out_size * sizeof(float), stream);
    long long tot = (long long)nnz * D;
    spmm_scatter_kernel<<<(int)((tot + 255) / 256), 256, 0, stream>>>(
        x, row, col, value, y, nnz);
    return;
  }

  char* ws = (char*)d_ws;
  int2*     pairs  = (int2*)ws;                         // nnz * 8B (8B aligned)
  unsigned* rs     = (unsigned*)(ws + (size_t)nnz * 8); // (n+1) * 4B
  unsigned* cursor = rs + (n + 1);                      // n * 4B

  // hist must start zeroed (ws is poisoned 0xAA before every launch).
  hipMemsetAsync(rs, 0, (size_t)(n + 1) * sizeof(unsigned), stream);

  int blocks_nnz = (nnz + 255) / 256;
  hist_kernel<<<blocks_nnz, 256, 0, stream>>>(row, rs, nnz);
  scan_kernel<<<1, 1024, 0, stream>>>(rs, cursor, n, nnz);
  scatter_kernel<<<blocks_nnz, 256, 0, stream>>>(row, col, value, cursor, pairs, nnz);

  long long tot = (long long)n * D;
  reduce_kernel<<<(int)((tot + 255) / 256), 256, 0, stream>>>(x, rs, pairs, y, n);
}